// Round 11
// baseline (413.598 us; speedup 1.0000x reference)
//
#include <hip/hip_runtime.h>
#include <math.h>

// Problem constants (LogitBiasedSelfAttention1D): B=4, C=512, T=2048, H=8, D=64
#define BB 4
#define CC 512
#define TT 2048
#define HH 8
#define DD 64
#define SCALE 0.125f
#define EPS 1e-5f

typedef __attribute__((ext_vector_type(8))) short bf16x8;   // 8 bf16 = 4 VGPRs (MFMA A/B frag)
typedef __attribute__((ext_vector_type(4))) float f32x4;    // MFMA C/D frag

__device__ inline ushort f2bf(float f) {           // RNE fp32 -> bf16
    unsigned int u = __builtin_bit_cast(unsigned int, f);
    u = (u + 0x7fff + ((u >> 16) & 1)) >> 16;
    return (ushort)u;
}
__device__ inline float bf2f(ushort u) {
    unsigned int v = ((unsigned int)u) << 16;
    return __builtin_bit_cast(float, v);
}
__device__ inline unsigned int pack2bf(float a, float b) {  // cheap near-RNE pack
    unsigned int ua = __builtin_bit_cast(unsigned int, a);
    unsigned int ub = __builtin_bit_cast(unsigned int, b);
    return ((ua + 0x8000u) >> 16) | ((ub + 0x8000u) & 0xffff0000u);
}

// async global->LDS, 16B per lane; lds base must be wave-uniform (HW adds lane*16)
typedef __attribute__((address_space(3))) unsigned int lds_uint;
typedef const __attribute__((address_space(1))) unsigned int glb_uint;
__device__ inline void gload16(void* lds_base, const void* gsrc) {
    __builtin_amdgcn_global_load_lds((glb_uint*)gsrc, (lds_uint*)lds_base, 16, 0, 0);
}

// ---------------------------------------------------------------- weight cast + conv->exp(bias)
__global__ void prep_k(const float* __restrict__ wq, const float* __restrict__ wo,
                       ushort* __restrict__ wqb, ushort* __restrict__ wob,
                       const float* __restrict__ sqi,
                       const float* __restrict__ wc, const float* __restrict__ bc,
                       float* __restrict__ ebias, ushort* __restrict__ ebf) {
    int idx = blockIdx.x * 256 + threadIdx.x;
    if (idx < 3 * CC * CC) wqb[idx] = f2bf(wq[idx]);
    else                   wob[idx - 3 * CC * CC] = f2bf(wo[idx - 3 * CC * CC]);
    if (idx < BB * TT) {
        int t = idx & (TT - 1);
        float l = (t > 0)      ? sqi[idx - 1] : 0.f;
        float m = sqi[idx];
        float r = (t < TT - 1) ? sqi[idx + 1] : 0.f;
        float eb = __expf(wc[0] * l + wc[1] * m + wc[2] * r + bc[0]);
        ebias[idx] = eb;
        ebf[idx] = f2bf(eb);
    }
}

// ---------------------------------------------------------------- x (b,c,t) fp32 -> xt (b,t,c) bf16
__global__ __launch_bounds__(256) void xt_cast_k(const float* __restrict__ x,
                                                 ushort* __restrict__ xt) {
    __shared__ float Ts[64][65];
    int tid = threadIdx.x;
    int t0 = blockIdx.x * 64, c0 = blockIdx.y * 64, b = blockIdx.z;
    int tl = tid & 63, r0 = tid >> 6;
    for (int k = 0; k < 16; ++k) {
        int cr = r0 * 16 + k;
        Ts[cr][tl] = x[((size_t)b * CC + c0 + cr) * TT + t0 + tl];
    }
    __syncthreads();
    int cl = tid & 63;
    for (int k = 0; k < 16; ++k) {
        int tw = r0 * 16 + k;
        xt[((size_t)b * TT + t0 + tw) * CC + c0 + cl] = f2bf(Ts[cl][tw]);
    }
}

// ---------------------------------------------------------------- QKV GEMM (bf16 MFMA, async staging) [R9 version]
// q -> (b,h,t,d) pre-scaled by SCALE; k -> (b,h,t,d); v -> (b,h,d,t) pre-scaled by exp(bias[t])
__global__ __launch_bounds__(256) void qkv_mfma_k(const ushort* __restrict__ xt,
                                                  const ushort* __restrict__ wqb,
                                                  const float* __restrict__ ebias,
                                                  ushort* __restrict__ qkv) {
    __shared__ ushort LDSb[17408];          // As[0..8192) Bs[8192..16384); epilogue 128x136
    ushort* As = LDSb;
    ushort* Bs = LDSb + 8192;
    int tid = threadIdx.x;
    int lane = tid & 63, w = tid >> 6;
    int wm = w & 1, wn = w >> 1;
    int m0 = blockIdx.x * 128;
    int j0 = blockIdx.y * 128;
    int b  = blockIdx.z;
    const ushort* Abase = xt + ((size_t)b * TT + m0) * CC;
    const ushort* Bbase = wqb + (size_t)j0 * CC;
    f32x4 acc[4][4];
    for (int mt = 0; mt < 4; ++mt)
        for (int nt = 0; nt < 4; ++nt)
            acc[mt][nt] = (f32x4){0.f, 0.f, 0.f, 0.f};

    int srow = (lane & 15), sch = (lane >> 4);
    for (int k0 = 0; k0 < CC; k0 += 64) {
        __syncthreads();
#pragma unroll
        for (int it = 0; it < 4; ++it) {
            int i = w * 4 + it;
            int row = (i >> 1) * 16 + srow;
            int ch  = (i & 1) * 4 + sch;
            gload16(&((uint4*)As)[i * 64], Abase + (size_t)row * CC + k0 + ch * 8);
            gload16(&((uint4*)Bs)[i * 64], Bbase + (size_t)row * CC + k0 + ch * 8);
        }
        __syncthreads();
#pragma unroll
        for (int ks = 0; ks < 2; ++ks) {
            bf16x8 af[4], bfr[4];
#pragma unroll
            for (int mt = 0; mt < 4; ++mt)
                af[mt] = *(const bf16x8*)&As[(((wm * 4 + mt) * 2 + ks) * 64 + lane) * 8];
#pragma unroll
            for (int nt = 0; nt < 4; ++nt)
                bfr[nt] = *(const bf16x8*)&Bs[(((wn * 4 + nt) * 2 + ks) * 64 + lane) * 8];
#pragma unroll
            for (int mt = 0; mt < 4; ++mt)
#pragma unroll
                for (int nt = 0; nt < 4; ++nt)
                    acc[mt][nt] = __builtin_amdgcn_mfma_f32_16x16x32_bf16(af[mt], bfr[nt], acc[mt][nt], 0, 0, 0);
        }
    }
    int which = j0 >> 9;
    int c = lane & 15, g = lane >> 4;
    __syncthreads();
    if (which < 2) {
        float qs = (which == 0) ? SCALE : 1.0f;
#pragma unroll
        for (int mt = 0; mt < 4; ++mt)
            for (int r = 0; r < 4; ++r) {
                int row = wm * 64 + mt * 16 + g * 4 + r;
                for (int nt = 0; nt < 4; ++nt)
                    LDSb[row * 136 + wn * 64 + nt * 16 + c] = f2bf(acc[mt][nt][r] * qs);
            }
    } else {
#pragma unroll
        for (int mt = 0; mt < 4; ++mt)
            for (int r = 0; r < 4; ++r) {
                int row = wm * 64 + mt * 16 + g * 4 + r;
                float eb = ebias[(size_t)b * TT + m0 + row];      // V' = exp(bias[t]) * v
                for (int nt = 0; nt < 4; ++nt)
                    LDSb[(wn * 64 + nt * 16 + c) * 136 + row] = f2bf(acc[mt][nt][r] * eb);
            }
    }
    __syncthreads();
    if (which < 2) {
        ushort* base = qkv + (size_t)(b * 3 + which) * HH * TT * DD;
#pragma unroll
        for (int it = 0; it < 8; ++it) {
            int f = it * 256 + tid;
            int row = f >> 4, ch = f & 15;
            uint4 val = *(const uint4*)&LDSb[row * 136 + ch * 8];
            int jj = (j0 & 511) + ch * 8;
            int h = jj >> 6, d = jj & 63;
            *(uint4*)(base + ((size_t)h * TT + m0 + row) * DD + d) = val;
        }
    } else {
        ushort* base = qkv + (size_t)(b * 3 + 2) * HH * TT * DD;
#pragma unroll
        for (int it = 0; it < 8; ++it) {
            int f = it * 256 + tid;
            int drow = f >> 4, tch = f & 15;
            uint4 val = *(const uint4*)&LDSb[drow * 136 + tch * 8];
            int jj = (j0 & 511) + drow;
            int h = jj >> 6, d = jj & 63;
            *(uint4*)(base + ((size_t)h * DD + d) * TT + m0 + tch * 8) = val;
        }
    }
}

// ---------------------------------------------------------------- attention (bf16 MFMA, barrier-free K-loop)
// K/V fragments loaded DIRECTLY from global (L2-resident, all waves read same tile);
// only Q (once), exp-bias (once), and wave-private P live in LDS -> no barriers in the loop.
// K frags double-buffered in registers; V single-buffered (used late in tile).
__global__ __launch_bounds__(256, 1) void attention_k(const ushort* __restrict__ qkv,
                                                      const ushort* __restrict__ ebf,
                                                      ushort* __restrict__ attnb) {
    __shared__ ushort QP[9216];     // Q stage (128x64, 16KB) then P[128][72] (aliased)
    __shared__ ushort ebs[2048];    // exp(bias) bf16, whole T for this b (4KB)
    int tid = threadIdx.x;
    int lane = tid & 63, w = tid >> 6;
    int c = lane & 15, g = lane >> 4;
    int q0 = blockIdx.x * 128, h = blockIdx.y, b = blockIdx.z;
    const ushort* qb = qkv + ((size_t)((b * 3 + 0) * HH + h)) * TT * DD;   // (t,d), pre-scaled
    const ushort* kb = qkv + ((size_t)((b * 3 + 1) * HH + h)) * TT * DD;   // (t,d)
    const ushort* vb = qkv + ((size_t)((b * 3 + 2) * HH + h)) * TT * DD;   // (d,t), eb-scaled

    // stage Q + full-T eb via async DMA, one barrier
#pragma unroll
    for (int it = 0; it < 4; ++it) {
        int i = w * 4 + it;
        int row = (i >> 1) * 16 + c;
        int ch  = (i & 1) * 4 + g;
        gload16(&((uint4*)QP)[i * 64], qb + (size_t)(q0 + row) * DD + ch * 8);
    }
    gload16(&((uint4*)ebs)[w * 64], ebf + (size_t)b * TT + w * 512 + lane * 8);
    __syncthreads();

    bf16x8 qfrag[2][2];
#pragma unroll
    for (int qg = 0; qg < 2; ++qg)
        for (int ks = 0; ks < 2; ++ks)
            qfrag[qg][ks] = *(const bf16x8*)&QP[(((qg * 4 + w) * 2 + ks) * 64 + lane) * 8];
    __syncthreads();   // all qfrags read before any wave's P writes clobber the Q region

    f32x4 oacc[2][4];
    f32x4 lacc[2];
    for (int qg = 0; qg < 2; ++qg) {
        lacc[qg] = (f32x4){0.f, 0.f, 0.f, 0.f};
        for (int dt = 0; dt < 4; ++dt) oacc[qg][dt] = (f32x4){0.f, 0.f, 0.f, 0.f};
    }

    // K frag register double-buffer; preload tile 0
    bf16x8 kf[2][4][2];
#pragma unroll
    for (int mt = 0; mt < 4; ++mt)
        for (int ks = 0; ks < 2; ++ks)
            kf[0][mt][ks] = *(const bf16x8*)(kb + (size_t)(mt * 16 + c) * DD + (ks * 4 + g) * 8);

    for (int i = 0; i < TT / 64; ++i) {
        int cur = i & 1;
        int s0 = i * 64;
        // V frags for this tile (used after S/exp phase -> latency hidden)
        bf16x8 vf[4][2];
#pragma unroll
        for (int dt = 0; dt < 4; ++dt)
            for (int ks = 0; ks < 2; ++ks)
                vf[dt][ks] = *(const bf16x8*)(vb + (size_t)(dt * 16 + c) * TT + s0 + (ks * 4 + g) * 8);
        // prefetch next K tile into the other register buffer
        if (i + 1 < TT / 64) {
            int s1 = s0 + 64;
#pragma unroll
            for (int mt = 0; mt < 4; ++mt)
                for (int ks = 0; ks < 2; ++ks)
                    kf[1 - cur][mt][ks] = *(const bf16x8*)(kb + (size_t)(s1 + mt * 16 + c) * DD + (ks * 4 + g) * 8);
        }
        bf16x8 ebfr[2];
#pragma unroll
        for (int ks = 0; ks < 2; ++ks)
            ebfr[ks] = *(const bf16x8*)&ebs[s0 + ks * 32 + g * 8];   // broadcast across c lanes

#pragma unroll
        for (int qg = 0; qg < 2; ++qg) {
            f32x4 st[4];
#pragma unroll
            for (int mt = 0; mt < 4; ++mt) {
                f32x4 acc = (f32x4){0.f, 0.f, 0.f, 0.f};
                for (int ks = 0; ks < 2; ++ks)
                    acc = __builtin_amdgcn_mfma_f32_16x16x32_bf16(kf[cur][mt][ks], qfrag[qg][ks], acc, 0, 0, 0);
                st[mt] = acc;
            }
            int qrow = (qg * 4 + w) * 16 + c;
#pragma unroll
            for (int mt = 0; mt < 4; ++mt) {
                uint2 pk;
                pk.x = pack2bf(__expf(st[mt][0]), __expf(st[mt][1]));
                pk.y = pack2bf(__expf(st[mt][2]), __expf(st[mt][3]));
                *(uint2*)&QP[qrow * 72 + mt * 16 + g * 4] = pk;
            }
        }

#pragma unroll
        for (int qg = 0; qg < 2; ++qg) {
            int qrow = (qg * 4 + w) * 16 + c;
            bf16x8 pb[2];
            for (int ks = 0; ks < 2; ++ks)
                pb[ks] = *(const bf16x8*)&QP[qrow * 72 + ks * 32 + g * 8];
#pragma unroll
            for (int dt = 0; dt < 4; ++dt) {
                f32x4 acc = oacc[qg][dt];
                for (int ks = 0; ks < 2; ++ks)
                    acc = __builtin_amdgcn_mfma_f32_16x16x32_bf16(vf[dt][ks], pb[ks], acc, 0, 0, 0);
                oacc[qg][dt] = acc;
            }
            for (int ks = 0; ks < 2; ++ks)
                lacc[qg] = __builtin_amdgcn_mfma_f32_16x16x32_bf16(ebfr[ks], pb[ks], lacc[qg], 0, 0, 0);
        }
    }
#pragma unroll
    for (int qg = 0; qg < 2; ++qg) {
        float inv = 1.f / lacc[qg][0];
        int t = q0 + (qg * 4 + w) * 16 + c;
        ushort* ob = attnb + ((size_t)b * TT + t) * CC + h * DD;
        for (int dt = 0; dt < 4; ++dt) {
            ushort4 pk;
            pk.x = f2bf(oacc[qg][dt][0] * inv); pk.y = f2bf(oacc[qg][dt][1] * inv);
            pk.z = f2bf(oacc[qg][dt][2] * inv); pk.w = f2bf(oacc[qg][dt][3] * inv);
            *(ushort4*)(ob + dt * 16 + g * 4) = pk;
        }
    }
}

// ---------------------------------------------------------------- fused out-proj + bias + residual + LN + transpose [R9 version]
// block = 32 t rows x full C (512); 4 waves, wave w owns n-slice [w*128, w*128+128)
__global__ __launch_bounds__(256) void oproj_ln_k(const ushort* __restrict__ attnb,
                                                  const ushort* __restrict__ wob,
                                                  const float* __restrict__ bout,
                                                  const ushort* __restrict__ xt,
                                                  const float* __restrict__ gamma,
                                                  const float* __restrict__ beta,
                                                  float* __restrict__ out) {
    __shared__ char smem[73728];            // GEMM: Asm 4KB + Bsm 64KB ; epilogue: TSo 512x36 fp32
    __shared__ float pstat[32][4][2];
    __shared__ float fstat[32][2];
    ushort* Asm = (ushort*)smem;
    ushort* Bsm = (ushort*)(smem + 4096);
    float* TSo = (float*)smem;
    int tid = threadIdx.x, lane = tid & 63, w = tid >> 6;
    int c = lane & 15, g = lane >> 4;
    int t0 = blockIdx.x * 32, b = blockIdx.y;
    const ushort* Abase = attnb + ((size_t)b * TT + t0) * CC;
    f32x4 acc[2][8];
    for (int mt = 0; mt < 2; ++mt)
        for (int nt = 0; nt < 8; ++nt)
            acc[mt][nt] = (f32x4){0.f, 0.f, 0.f, 0.f};

    for (int k0 = 0; k0 < CC; k0 += 64) {
        __syncthreads();
        {   // A tile (32 x 64): wave w stages slot-group w
            int row = (w >> 1) * 16 + c;
            int ch  = (w & 1) * 4 + g;
            gload16(&((uint4*)Asm)[w * 64], Abase + (size_t)row * CC + k0 + ch * 8);
        }
#pragma unroll
        for (int gi2 = 0; gi2 < 2; ++gi2) {     // B tile (512 x 64): wave stages 2 row-groups of 64
            int gi = w * 2 + gi2;
#pragma unroll
            for (int i = 0; i < 8; ++i) {
                int row = gi * 64 + (i >> 1) * 16 + c;
                int ch  = (i & 1) * 4 + g;
                gload16(&((uint4*)Bsm)[gi * 512 + i * 64], wob + (size_t)row * CC + k0 + ch * 8);
            }
        }
        __syncthreads();
#pragma unroll
        for (int ks = 0; ks < 2; ++ks) {
            bf16x8 af[2], bfr[8];
#pragma unroll
            for (int mt = 0; mt < 2; ++mt)
                af[mt] = *(const bf16x8*)&Asm[((mt * 2 + ks) * 64 + lane) * 8];
#pragma unroll
            for (int nt = 0; nt < 8; ++nt)
                bfr[nt] = *(const bf16x8*)&Bsm[(w * 2 + (nt >> 2)) * 4096 + (((nt & 3) * 2 + ks) * 64 + lane) * 8];
#pragma unroll
            for (int mt = 0; mt < 2; ++mt)
#pragma unroll
                for (int nt = 0; nt < 8; ++nt)
                    acc[mt][nt] = __builtin_amdgcn_mfma_f32_16x16x32_bf16(af[mt], bfr[nt], acc[mt][nt], 0, 0, 0);
        }
    }
    // h = acc + bias + residual (in registers), per-row partial LN stats
    float bo[8], gam[8], bet[8];
#pragma unroll
    for (int nt = 0; nt < 8; ++nt) {
        int i = w * 128 + nt * 16 + c;
        bo[nt] = bout[i]; gam[nt] = gamma[i]; bet[nt] = beta[i];
    }
#pragma unroll
    for (int mt = 0; mt < 2; ++mt)
        for (int r = 0; r < 4; ++r) {
            int tl = mt * 16 + g * 4 + r;
            const ushort* xr = xt + ((size_t)b * TT + t0 + tl) * CC;
            float s = 0.f, sq = 0.f;
            for (int nt = 0; nt < 8; ++nt) {
                int i = w * 128 + nt * 16 + c;
                float hv = acc[mt][nt][r] + bo[nt] + bf2f(xr[i]);
                acc[mt][nt][r] = hv;
                s += hv; sq += hv * hv;
            }
            s += __shfl_xor(s, 1);  sq += __shfl_xor(sq, 1);
            s += __shfl_xor(s, 2);  sq += __shfl_xor(sq, 2);
            s += __shfl_xor(s, 4);  sq += __shfl_xor(sq, 4);
            s += __shfl_xor(s, 8);  sq += __shfl_xor(sq, 8);
            if (c == 0) { pstat[tl][w][0] = s; pstat[tl][w][1] = sq; }
        }
    __syncthreads();
    if (tid < 32) {
        float s  = pstat[tid][0][0] + pstat[tid][1][0] + pstat[tid][2][0] + pstat[tid][3][0];
        float sq = pstat[tid][0][1] + pstat[tid][1][1] + pstat[tid][2][1] + pstat[tid][3][1];
        float m = s * (1.0f / CC);
        float var = sq * (1.0f / CC) - m * m;
        fstat[tid][0] = m;
        fstat[tid][1] = rsqrtf(var + EPS);
    }
    __syncthreads();
    // normalize + transpose via LDS (TSo aliases the GEMM stage; all reads done)
#pragma unroll
    for (int mt = 0; mt < 2; ++mt)
        for (int r = 0; r < 4; ++r) {
            int tl = mt * 16 + g * 4 + r;
            float m = fstat[tl][0], rs = fstat[tl][1];
            for (int nt = 0; nt < 8; ++nt) {
                int i = w * 128 + nt * 16 + c;
                float hn = (acc[mt][nt][r] - m) * rs * gam[nt] + bet[nt];
                TSo[i * 36 + tl] = hn;
            }
        }
    __syncthreads();
#pragma unroll
    for (int it = 0; it < 16; ++it) {
        int idx = it * 256 + tid;
        int ci = idx >> 3, tch = idx & 7;
        float4 v = *(const float4*)&TSo[ci * 36 + tch * 4];
        *(float4*)&out[((size_t)b * CC + ci) * TT + t0 + tch * 4] = v;
    }
}

// ----------------------------------------------------------------
extern "C" void kernel_launch(void* const* d_in, const int* in_sizes, int n_in,
                              void* d_out, int out_size, void* d_ws, size_t ws_size,
                              hipStream_t stream) {
    const float* x      = (const float*)d_in[0];
    const float* sqi    = (const float*)d_in[1];
    const float* w_qkv  = (const float*)d_in[2];
    const float* w_out  = (const float*)d_in[3];
    const float* b_out  = (const float*)d_in[4];
    const float* w_conv = (const float*)d_in[5];
    const float* b_conv = (const float*)d_in[6];
    const float* gamma  = (const float*)d_in[7];
    const float* beta   = (const float*)d_in[8];
    float* out = (float*)d_out;

    ushort* qkvbuf = (ushort*)d_ws;                          // B*3*C*T bf16 (25.2MB)
    ushort* xt     = qkvbuf + (size_t)BB * 3 * CC * TT;      // B*T*C bf16 (8.4MB)
    ushort* attnb  = xt + (size_t)BB * TT * CC;              // B*T*C bf16 (8.4MB)
    ushort* wqb    = attnb + (size_t)BB * TT * CC;           // 3C*C bf16
    ushort* wob    = wqb + 3 * CC * CC;                      // C*C bf16
    ushort* ebf    = wob + CC * CC;                          // B*T bf16
    float*  ebias  = (float*)(ebf + BB * TT);                // B*T fp32

    prep_k<<<dim3((4 * CC * CC) / 256), 256, 0, stream>>>(w_qkv, w_out, wqb, wob,
                                                          sqi, w_conv, b_conv, ebias, ebf);
    xt_cast_k<<<dim3(TT / 64, CC / 64, BB), 256, 0, stream>>>(x, xt);
    qkv_mfma_k<<<dim3(TT / 128, (3 * CC) / 128, BB), 256, 0, stream>>>(xt, wqb, ebias, qkvbuf);
    attention_k<<<dim3(TT / 128, HH, BB), 256, 0, stream>>>(qkvbuf, ebf, attnb);
    oproj_ln_k<<<dim3(TT / 32, BB), 256, 0, stream>>>(attnb, wob, b_out, xt, gamma, beta, out);
}

// Round 12
// 203.672 us; speedup vs baseline: 2.0307x; 2.0307x over previous
//
#include <hip/hip_runtime.h>
#include <math.h>

// Problem constants (LogitBiasedSelfAttention1D): B=4, C=512, T=2048, H=8, D=64
#define BB 4
#define CC 512
#define TT 2048
#define HH 8
#define DD 64
#define SCALE 0.125f
#define EPS 1e-5f

typedef __attribute__((ext_vector_type(8))) short bf16x8;   // 8 bf16 = 4 VGPRs (MFMA A/B frag)
typedef __attribute__((ext_vector_type(4))) float f32x4;    // MFMA C/D frag

__device__ inline ushort f2bf(float f) {           // RNE fp32 -> bf16
    unsigned int u = __builtin_bit_cast(unsigned int, f);
    u = (u + 0x7fff + ((u >> 16) & 1)) >> 16;
    return (ushort)u;
}
__device__ inline float bf2f(ushort u) {
    unsigned int v = ((unsigned int)u) << 16;
    return __builtin_bit_cast(float, v);
}
__device__ inline unsigned int pack2bf(float a, float b) {  // cheap near-RNE pack
    unsigned int ua = __builtin_bit_cast(unsigned int, a);
    unsigned int ub = __builtin_bit_cast(unsigned int, b);
    return ((ua + 0x8000u) >> 16) | ((ub + 0x8000u) & 0xffff0000u);
}

// async global->LDS, 16B per lane; lds base must be wave-uniform (HW adds lane*16)
typedef __attribute__((address_space(3))) unsigned int lds_uint;
typedef const __attribute__((address_space(1))) unsigned int glb_uint;
__device__ inline void gload16(void* lds_base, const void* gsrc) {
    __builtin_amdgcn_global_load_lds((glb_uint*)gsrc, (lds_uint*)lds_base, 16, 0, 0);
}

// ---------------------------------------------------------------- weight cast + conv->exp(bias)
__global__ void prep_k(const float* __restrict__ wq, const float* __restrict__ wo,
                       ushort* __restrict__ wqb, ushort* __restrict__ wob,
                       const float* __restrict__ sqi,
                       const float* __restrict__ wc, const float* __restrict__ bc,
                       float* __restrict__ ebias, ushort* __restrict__ ebf) {
    int idx = blockIdx.x * 256 + threadIdx.x;
    if (idx < 3 * CC * CC) wqb[idx] = f2bf(wq[idx]);
    else                   wob[idx - 3 * CC * CC] = f2bf(wo[idx - 3 * CC * CC]);
    if (idx < BB * TT) {
        int t = idx & (TT - 1);
        float l = (t > 0)      ? sqi[idx - 1] : 0.f;
        float m = sqi[idx];
        float r = (t < TT - 1) ? sqi[idx + 1] : 0.f;
        float eb = __expf(wc[0] * l + wc[1] * m + wc[2] * r + bc[0]);
        ebias[idx] = eb;
        ebf[idx] = f2bf(eb);
    }
}

// ---------------------------------------------------------------- x (b,c,t) fp32 -> xt (b,t,c) bf16
__global__ __launch_bounds__(256) void xt_cast_k(const float* __restrict__ x,
                                                 ushort* __restrict__ xt) {
    __shared__ float Ts[64][65];
    int tid = threadIdx.x;
    int t0 = blockIdx.x * 64, c0 = blockIdx.y * 64, b = blockIdx.z;
    int tl = tid & 63, r0 = tid >> 6;
    for (int k = 0; k < 16; ++k) {
        int cr = r0 * 16 + k;
        Ts[cr][tl] = x[((size_t)b * CC + c0 + cr) * TT + t0 + tl];
    }
    __syncthreads();
    int cl = tid & 63;
    for (int k = 0; k < 16; ++k) {
        int tw = r0 * 16 + k;
        xt[((size_t)b * TT + t0 + tw) * CC + c0 + cl] = f2bf(Ts[cl][tw]);
    }
}

// ---------------------------------------------------------------- QKV GEMM (bf16 MFMA, BK=64 depth-2 dbuf)
// q -> (b,h,t,d) pre-scaled by SCALE; k -> (b,h,t,d); v -> (b,h,d,t) pre-scaled by exp(bias[t])
// ONE barrier per K-step; stage(i+1) overlaps compute(i). Epilogue aliases dbuf.
__global__ __launch_bounds__(256) void qkv_mfma_k(const ushort* __restrict__ xt,
                                                  const ushort* __restrict__ wqb,
                                                  const float* __restrict__ ebias,
                                                  ushort* __restrict__ qkv) {
    __shared__ ushort LDSb[32768];   // 64KB: buf q at q*16384 (A 8192 + B 8192); epilogue [0,17408)
    int tid = threadIdx.x;
    int lane = tid & 63, w = tid >> 6;
    int wm = w & 1, wn = w >> 1;
    int m0 = blockIdx.x * 128;
    int j0 = blockIdx.y * 128;
    int b  = blockIdx.z;
    const ushort* Abase = xt + ((size_t)b * TT + m0) * CC;
    const ushort* Bbase = wqb + (size_t)j0 * CC;
    f32x4 acc[4][4];
    for (int mt = 0; mt < 4; ++mt)
        for (int nt = 0; nt < 4; ++nt)
            acc[mt][nt] = (f32x4){0.f, 0.f, 0.f, 0.f};

    int srow = lane & 15, sch = lane >> 4;
    {   // stage step 0 into buf 0
        ushort* As = LDSb;
        ushort* Bs = LDSb + 8192;
#pragma unroll
        for (int it = 0; it < 4; ++it) {
            int i = w * 4 + it;
            int row = (i >> 1) * 16 + srow;
            int ch  = (i & 1) * 4 + sch;
            gload16(&((uint4*)As)[i * 64], Abase + (size_t)row * CC + ch * 8);
            gload16(&((uint4*)Bs)[i * 64], Bbase + (size_t)row * CC + ch * 8);
        }
    }
    __syncthreads();

    for (int i = 0; i < 8; ++i) {
        int cur = i & 1;
        if (i) __syncthreads();              // stage(i) landed; buf cur free of old readers
        if (i + 1 < 8) {                     // stage(i+1) into other buf (async, overlaps compute)
            int k1 = (i + 1) * 64;
            ushort* As = LDSb + (1 - cur) * 16384;
            ushort* Bs = As + 8192;
#pragma unroll
            for (int it = 0; it < 4; ++it) {
                int s = w * 4 + it;
                int row = (s >> 1) * 16 + srow;
                int ch  = (s & 1) * 4 + sch;
                gload16(&((uint4*)As)[s * 64], Abase + (size_t)row * CC + k1 + ch * 8);
                gload16(&((uint4*)Bs)[s * 64], Bbase + (size_t)row * CC + k1 + ch * 8);
            }
        }
        const ushort* As = LDSb + cur * 16384;
        const ushort* Bs = As + 8192;
#pragma unroll
        for (int ks = 0; ks < 2; ++ks) {
            bf16x8 af[4], bfr[4];
#pragma unroll
            for (int mt = 0; mt < 4; ++mt)
                af[mt] = *(const bf16x8*)&As[(((wm * 4 + mt) * 2 + ks) * 64 + lane) * 8];
#pragma unroll
            for (int nt = 0; nt < 4; ++nt)
                bfr[nt] = *(const bf16x8*)&Bs[(((wn * 4 + nt) * 2 + ks) * 64 + lane) * 8];
#pragma unroll
            for (int mt = 0; mt < 4; ++mt)
#pragma unroll
                for (int nt = 0; nt < 4; ++nt)
                    acc[mt][nt] = __builtin_amdgcn_mfma_f32_16x16x32_bf16(af[mt], bfr[nt], acc[mt][nt], 0, 0, 0);
        }
    }
    int which = j0 >> 9;
    int c = lane & 15, g = lane >> 4;
    __syncthreads();
    if (which < 2) {
        float qs = (which == 0) ? SCALE : 1.0f;
#pragma unroll
        for (int mt = 0; mt < 4; ++mt)
            for (int r = 0; r < 4; ++r) {
                int row = wm * 64 + mt * 16 + g * 4 + r;
                for (int nt = 0; nt < 4; ++nt)
                    LDSb[row * 136 + wn * 64 + nt * 16 + c] = f2bf(acc[mt][nt][r] * qs);
            }
    } else {
#pragma unroll
        for (int mt = 0; mt < 4; ++mt)
            for (int r = 0; r < 4; ++r) {
                int row = wm * 64 + mt * 16 + g * 4 + r;
                float eb = ebias[(size_t)b * TT + m0 + row];      // V' = exp(bias[t]) * v
                for (int nt = 0; nt < 4; ++nt)
                    LDSb[(wn * 64 + nt * 16 + c) * 136 + row] = f2bf(acc[mt][nt][r] * eb);
            }
    }
    __syncthreads();
    if (which < 2) {
        ushort* base = qkv + (size_t)(b * 3 + which) * HH * TT * DD;
#pragma unroll
        for (int it = 0; it < 8; ++it) {
            int f = it * 256 + tid;
            int row = f >> 4, ch = f & 15;
            uint4 val = *(const uint4*)&LDSb[row * 136 + ch * 8];
            int jj = (j0 & 511) + ch * 8;
            int h = jj >> 6, d = jj & 63;
            *(uint4*)(base + ((size_t)h * TT + m0 + row) * DD + d) = val;
        }
    } else {
        ushort* base = qkv + (size_t)(b * 3 + 2) * HH * TT * DD;
#pragma unroll
        for (int it = 0; it < 8; ++it) {
            int f = it * 256 + tid;
            int drow = f >> 4, tch = f & 15;
            uint4 val = *(const uint4*)&LDSb[drow * 136 + tch * 8];
            int jj = (j0 & 511) + drow;
            int h = jj >> 6, d = jj & 63;
            *(uint4*)(base + ((size_t)h * DD + d) * TT + m0 + tch * 8) = val;
        }
    }
}

// ---------------------------------------------------------------- attention (bf16 MFMA, depth-2 pipeline) [R9, 64.5us]
// P = exp(q_scaled·k); l = P·exp(bias) via MFMA; V pre-scaled by exp(bias); out = (P·V')/l
__global__ __launch_bounds__(256, 2) void attention_k(const ushort* __restrict__ qkv,
                                                      const ushort* __restrict__ ebf,
                                                      ushort* __restrict__ attnb) {
    __shared__ ushort QP[9216];        // Q stage (128x64), then P[128][72] (aliased)
    __shared__ ushort Kf[2][4096];
    __shared__ ushort Vf[2][4096];
    __shared__ ushort ebs[2][64];
    int tid = threadIdx.x;
    int lane = tid & 63, w = tid >> 6;
    int c = lane & 15, g = lane >> 4;
    int q0 = blockIdx.x * 128, h = blockIdx.y, b = blockIdx.z;
    const ushort* qb = qkv + ((size_t)((b * 3 + 0) * HH + h)) * TT * DD;   // (t,d), pre-scaled
    const ushort* kb = qkv + ((size_t)((b * 3 + 1) * HH + h)) * TT * DD;   // (t,d)
    const ushort* vb = qkv + ((size_t)((b * 3 + 2) * HH + h)) * TT * DD;   // (d,t), eb-scaled

#pragma unroll
    for (int it = 0; it < 4; ++it) {
        int i = w * 4 + it;
        int row = (i >> 1) * 16 + c;
        int ch  = (i & 1) * 4 + g;
        gload16(&((uint4*)QP)[i * 64], qb + (size_t)(q0 + row) * DD + ch * 8);
    }
#pragma unroll
    for (int it = 0; it < 2; ++it) {
        int i = w * 2 + it;
        int row = (i >> 1) * 16 + c;
        int ch  = (i & 1) * 4 + g;
        gload16(&((uint4*)Kf[0])[i * 64], kb + (size_t)row * DD + ch * 8);
        gload16(&((uint4*)Vf[0])[i * 64], vb + (size_t)row * TT + ch * 8);
    }
    if (tid < 32) ((uint*)ebs[0])[tid] = *((const uint*)(ebf + (size_t)b * TT) + tid);
    __syncthreads();

    bf16x8 qfrag[2][2];
    for (int qg = 0; qg < 2; ++qg)
        for (int ks = 0; ks < 2; ++ks)
            qfrag[qg][ks] = *(const bf16x8*)&QP[(((qg * 4 + w) * 2 + ks) * 64 + lane) * 8];

    f32x4 oacc[2][4];
    f32x4 lacc[2];
    for (int qg = 0; qg < 2; ++qg) {
        lacc[qg] = (f32x4){0.f, 0.f, 0.f, 0.f};
        for (int dt = 0; dt < 4; ++dt) oacc[qg][dt] = (f32x4){0.f, 0.f, 0.f, 0.f};
    }

    for (int i = 0; i < TT / 64; ++i) {
        int cur = i & 1;
        if (i) __syncthreads();
        if (i + 1 < TT / 64) {
            int s1 = (i + 1) * 64;
#pragma unroll
            for (int it = 0; it < 2; ++it) {
                int idx = w * 2 + it;
                int row = (idx >> 1) * 16 + c;
                int ch  = (idx & 1) * 4 + g;
                gload16(&((uint4*)Kf[1 - cur])[idx * 64], kb + (size_t)(s1 + row) * DD + ch * 8);
                gload16(&((uint4*)Vf[1 - cur])[idx * 64], vb + (size_t)row * TT + s1 + ch * 8);
            }
            if (tid < 32) ((uint*)ebs[1 - cur])[tid] = *((const uint*)(ebf + (size_t)b * TT + s1) + tid);
        }

        bf16x8 kf[4][2];
#pragma unroll
        for (int mt = 0; mt < 4; ++mt)
            for (int ks = 0; ks < 2; ++ks)
                kf[mt][ks] = *(const bf16x8*)&Kf[cur][((mt * 2 + ks) * 64 + lane) * 8];

#pragma unroll
        for (int qg = 0; qg < 2; ++qg) {
            f32x4 st[4];
#pragma unroll
            for (int mt = 0; mt < 4; ++mt) {
                f32x4 acc = (f32x4){0.f, 0.f, 0.f, 0.f};
                for (int ks = 0; ks < 2; ++ks)
                    acc = __builtin_amdgcn_mfma_f32_16x16x32_bf16(kf[mt][ks], qfrag[qg][ks], acc, 0, 0, 0);
                st[mt] = acc;
            }
            int qrow = (qg * 4 + w) * 16 + c;
#pragma unroll
            for (int mt = 0; mt < 4; ++mt) {
                uint2 pk;
                pk.x = pack2bf(__expf(st[mt][0]), __expf(st[mt][1]));
                pk.y = pack2bf(__expf(st[mt][2]), __expf(st[mt][3]));
                *(uint2*)&QP[qrow * 72 + mt * 16 + g * 4] = pk;
            }
        }

        bf16x8 vf[4][2], ebfr[2];
#pragma unroll
        for (int dt = 0; dt < 4; ++dt)
            for (int ks = 0; ks < 2; ++ks)
                vf[dt][ks] = *(const bf16x8*)&Vf[cur][((dt * 2 + ks) * 64 + lane) * 8];
        for (int ks = 0; ks < 2; ++ks)
            ebfr[ks] = *(const bf16x8*)&ebs[cur][ks * 32 + g * 8];   // broadcast across c lanes

#pragma unroll
        for (int qg = 0; qg < 2; ++qg) {
            int qrow = (qg * 4 + w) * 16 + c;
            bf16x8 pb[2];
            for (int ks = 0; ks < 2; ++ks)
                pb[ks] = *(const bf16x8*)&QP[qrow * 72 + ks * 32 + g * 8];
#pragma unroll
            for (int dt = 0; dt < 4; ++dt) {
                f32x4 acc = oacc[qg][dt];
                for (int ks = 0; ks < 2; ++ks)
                    acc = __builtin_amdgcn_mfma_f32_16x16x32_bf16(vf[dt][ks], pb[ks], acc, 0, 0, 0);
                oacc[qg][dt] = acc;
            }
            for (int ks = 0; ks < 2; ++ks)
                lacc[qg] = __builtin_amdgcn_mfma_f32_16x16x32_bf16(ebfr[ks], pb[ks], lacc[qg], 0, 0, 0);
        }
    }
#pragma unroll
    for (int qg = 0; qg < 2; ++qg) {
        float inv = 1.f / lacc[qg][0];
        int t = q0 + (qg * 4 + w) * 16 + c;
        ushort* ob = attnb + ((size_t)b * TT + t) * CC + h * DD;
        for (int dt = 0; dt < 4; ++dt) {
            ushort4 pk;
            pk.x = f2bf(oacc[qg][dt][0] * inv); pk.y = f2bf(oacc[qg][dt][1] * inv);
            pk.z = f2bf(oacc[qg][dt][2] * inv); pk.w = f2bf(oacc[qg][dt][3] * inv);
            *(ushort4*)(ob + dt * 16 + g * 4) = pk;
        }
    }
}

// ---------------------------------------------------------------- fused out-proj + bias + residual + LN + transpose
// block = 32 t rows x full C; BK=32 depth-2 dbuf, ONE barrier per K-step.
__global__ __launch_bounds__(256) void oproj_ln_k(const ushort* __restrict__ attnb,
                                                  const ushort* __restrict__ wob,
                                                  const float* __restrict__ bout,
                                                  const ushort* __restrict__ xt,
                                                  const float* __restrict__ gamma,
                                                  const float* __restrict__ beta,
                                                  float* __restrict__ out) {
    __shared__ char smem[73728];            // dbuf: buf q at q*34816 B (A 2KB + B 32KB); epilogue TSo 512x36 fp32
    __shared__ float pstat[32][4][2];
    __shared__ float fstat[32][2];
    float* TSo = (float*)smem;
    int tid = threadIdx.x, lane = tid & 63, w = tid >> 6;
    int c = lane & 15, g = lane >> 4;
    int t0 = blockIdx.x * 32, b = blockIdx.y;
    const ushort* Abase = attnb + ((size_t)b * TT + t0) * CC;
    f32x4 acc[2][8];
    for (int mt = 0; mt < 2; ++mt)
        for (int nt = 0; nt < 8; ++nt)
            acc[mt][nt] = (f32x4){0.f, 0.f, 0.f, 0.f};

    {   // stage step 0 into buf 0
        ushort* A0 = (ushort*)smem;
        ushort* B0 = A0 + 1024;
        if (w < 2)
            gload16(&((uint4*)A0)[w * 64], Abase + (size_t)(w * 16 + c) * CC + g * 8);
#pragma unroll
        for (int j = 0; j < 8; ++j) {
            int gi = w * 8 + j;
            gload16(&((uint4*)B0)[gi * 64], wob + (size_t)(gi * 16 + c) * CC + g * 8);
        }
    }
    __syncthreads();

    for (int i = 0; i < 16; ++i) {
        int cur = i & 1;
        if (i) __syncthreads();
        if (i + 1 < 16) {
            int k1 = (i + 1) * 32;
            ushort* A1 = (ushort*)smem + (size_t)(1 - cur) * 17408;
            ushort* B1 = A1 + 1024;
            if (w < 2)
                gload16(&((uint4*)A1)[w * 64], Abase + (size_t)(w * 16 + c) * CC + k1 + g * 8);
#pragma unroll
            for (int j = 0; j < 8; ++j) {
                int gi = w * 8 + j;
                gload16(&((uint4*)B1)[gi * 64], wob + (size_t)(gi * 16 + c) * CC + k1 + g * 8);
            }
        }
        const ushort* A = (const ushort*)smem + (size_t)cur * 17408;
        const ushort* Bm = A + 1024;
        bf16x8 af[2], bfr[8];
#pragma unroll
        for (int mt = 0; mt < 2; ++mt)
            af[mt] = *(const bf16x8*)&A[(mt * 64 + lane) * 8];
#pragma unroll
        for (int nt = 0; nt < 8; ++nt)
            bfr[nt] = *(const bf16x8*)&Bm[((w * 8 + nt) * 64 + lane) * 8];
#pragma unroll
        for (int mt = 0; mt < 2; ++mt)
#pragma unroll
            for (int nt = 0; nt < 8; ++nt)
                acc[mt][nt] = __builtin_amdgcn_mfma_f32_16x16x32_bf16(af[mt], bfr[nt], acc[mt][nt], 0, 0, 0);
    }
    // h = acc + bias + residual (in registers), per-row partial LN stats
    float bo[8], gam[8], bet[8];
#pragma unroll
    for (int nt = 0; nt < 8; ++nt) {
        int i = w * 128 + nt * 16 + c;
        bo[nt] = bout[i]; gam[nt] = gamma[i]; bet[nt] = beta[i];
    }
#pragma unroll
    for (int mt = 0; mt < 2; ++mt)
        for (int r = 0; r < 4; ++r) {
            int tl = mt * 16 + g * 4 + r;
            const ushort* xr = xt + ((size_t)b * TT + t0 + tl) * CC;
            float s = 0.f, sq = 0.f;
            for (int nt = 0; nt < 8; ++nt) {
                int i = w * 128 + nt * 16 + c;
                float hv = acc[mt][nt][r] + bo[nt] + bf2f(xr[i]);
                acc[mt][nt][r] = hv;
                s += hv; sq += hv * hv;
            }
            s += __shfl_xor(s, 1);  sq += __shfl_xor(sq, 1);
            s += __shfl_xor(s, 2);  sq += __shfl_xor(sq, 2);
            s += __shfl_xor(s, 4);  sq += __shfl_xor(sq, 4);
            s += __shfl_xor(s, 8);  sq += __shfl_xor(sq, 8);
            if (c == 0) { pstat[tl][w][0] = s; pstat[tl][w][1] = sq; }
        }
    __syncthreads();
    if (tid < 32) {
        float s  = pstat[tid][0][0] + pstat[tid][1][0] + pstat[tid][2][0] + pstat[tid][3][0];
        float sq = pstat[tid][0][1] + pstat[tid][1][1] + pstat[tid][2][1] + pstat[tid][3][1];
        float m = s * (1.0f / CC);
        float var = sq * (1.0f / CC) - m * m;
        fstat[tid][0] = m;
        fstat[tid][1] = rsqrtf(var + EPS);
    }
    __syncthreads();
    // normalize + transpose via LDS (TSo aliases the dbuf; all GEMM reads done)
#pragma unroll
    for (int mt = 0; mt < 2; ++mt)
        for (int r = 0; r < 4; ++r) {
            int tl = mt * 16 + g * 4 + r;
            float m = fstat[tl][0], rs = fstat[tl][1];
            for (int nt = 0; nt < 8; ++nt) {
                int i = w * 128 + nt * 16 + c;
                float hn = (acc[mt][nt][r] - m) * rs * gam[nt] + bet[nt];
                TSo[i * 36 + tl] = hn;
            }
        }
    __syncthreads();
#pragma unroll
    for (int it = 0; it < 16; ++it) {
        int idx = it * 256 + tid;
        int ci = idx >> 3, tch = idx & 7;
        float4 v = *(const float4*)&TSo[ci * 36 + tch * 4];
        *(float4*)&out[((size_t)b * CC + ci) * TT + t0 + tch * 4] = v;
    }
}

// ----------------------------------------------------------------
extern "C" void kernel_launch(void* const* d_in, const int* in_sizes, int n_in,
                              void* d_out, int out_size, void* d_ws, size_t ws_size,
                              hipStream_t stream) {
    const float* x      = (const float*)d_in[0];
    const float* sqi    = (const float*)d_in[1];
    const float* w_qkv  = (const float*)d_in[2];
    const float* w_out  = (const float*)d_in[3];
    const float* b_out  = (const float*)d_in[4];
    const float* w_conv = (const float*)d_in[5];
    const float* b_conv = (const float*)d_in[6];
    const float* gamma  = (const float*)d_in[7];
    const float* beta   = (const float*)d_in[8];
    float* out = (float*)d_out;

    ushort* qkvbuf = (ushort*)d_ws;                          // B*3*C*T bf16 (25.2MB)
    ushort* xt     = qkvbuf + (size_t)BB * 3 * CC * TT;      // B*T*C bf16 (8.4MB)
    ushort* attnb  = xt + (size_t)BB * TT * CC;              // B*T*C bf16 (8.4MB)
    ushort* wqb    = attnb + (size_t)BB * TT * CC;           // 3C*C bf16
    ushort* wob    = wqb + 3 * CC * CC;                      // C*C bf16
    ushort* ebf    = wob + CC * CC;                          // B*T bf16
    float*  ebias  = (float*)(ebf + BB * TT);                // B*T fp32

    prep_k<<<dim3((4 * CC * CC) / 256), 256, 0, stream>>>(w_qkv, w_out, wqb, wob,
                                                          sqi, w_conv, b_conv, ebias, ebf);
    xt_cast_k<<<dim3(TT / 64, CC / 64, BB), 256, 0, stream>>>(x, xt);
    qkv_mfma_k<<<dim3(TT / 128, (3 * CC) / 128, BB), 256, 0, stream>>>(xt, wqb, ebias, qkvbuf);
    attention_k<<<dim3(TT / 128, HH, BB), 256, 0, stream>>>(qkvbuf, ebf, attnb);
    oproj_ln_k<<<dim3(TT / 32, BB), 256, 0, stream>>>(attnb, wob, b_out, xt, gamma, beta, out);
}